// Round 7
// baseline (734.789 us; speedup 1.0000x reference)
//
#include <hip/hip_runtime.h>
#include <math.h>

#define NNODES 100000
#define NEDGES 3200000
#define F 128
#define NPB 512
#define NB ((NNODES + NPB - 1) / NPB)   // 196 buckets
#define CAP 20480                        // slots per bucket (mean 16326, 32 sigma margin)
#define T2 8192
#define NKEY (NPB * 16)                  // (dst-local 9b) x (src-range 4b) counting-sort keys
#define NRANGE 13                        // src ranges of 8192 nodes (100000 -> 13 ranges)

typedef __attribute__((ext_vector_type(8))) short short8;
typedef __attribute__((ext_vector_type(4))) float f32x4;

__device__ __forceinline__ unsigned short f2bf(float f) {
    unsigned u = __float_as_uint(f);
    unsigned r = u + 0x7fff + ((u >> 16) & 1);
    return (unsigned short)(r >> 16);
}
__device__ __forceinline__ float bflo(unsigned u) { return __uint_as_float(u << 16); }
__device__ __forceinline__ float bfhi(unsigned u) { return __uint_as_float(u & 0xffff0000u); }

// ---------------- cursor init (CAP-strided bucket bases) ----------------

__global__ void init_cursors_kernel(int* __restrict__ dcur, int* __restrict__ scur) {
    int b = blockIdx.x * 256 + threadIdx.x;
    if (b < NB) { dcur[b] = b * CAP; scur[b] = b * CAP; }
}

// ---------------- dual binning: one edge read -> dst-keyed + src-keyed bins ----------------

__global__ __launch_bounds__(256) void dual_bin_kernel(const int* __restrict__ src,
                                                       const int* __restrict__ dst,
                                                       int* __restrict__ dcur,
                                                       int* __restrict__ scur,
                                                       unsigned* __restrict__ epk,
                                                       unsigned short* __restrict__ esl) {
    __shared__ unsigned pk[T2];
    __shared__ unsigned short sl[T2];
    __shared__ unsigned char db[T2], sb[T2];
    __shared__ int dh[NB], dbase[NB], dlc[NB];
    __shared__ int sh[NB], sbase[NB], slc[NB];
    int t = threadIdx.x;
    for (int i = t; i < NB; i += 256) { dh[i] = 0; dlc[i] = 0; sh[i] = 0; slc[i] = 0; }
    __syncthreads();
    int e0 = blockIdx.x * T2;
    int n = min(T2, NEDGES - e0);
    for (int i = t; i < n; i += 256) {
        int s = src[e0 + i], d = dst[e0 + i];
        int bd = d >> 9, bs = s >> 9;
        pk[i] = (unsigned)s | ((unsigned)(d & 511) << 17);
        sl[i] = (unsigned short)(s & 511);
        db[i] = (unsigned char)bd;
        sb[i] = (unsigned char)bs;
        atomicAdd(&dh[bd], 1);
        atomicAdd(&sh[bs], 1);
    }
    __syncthreads();
    for (int b = t; b < NB; b += 256) {
        if (dh[b]) dbase[b] = atomicAdd(&dcur[b], dh[b]);
        if (sh[b]) sbase[b] = atomicAdd(&scur[b], sh[b]);
    }
    __syncthreads();
    for (int i = t; i < n; i += 256) {
        int b = db[i];
        epk[dbase[b] + atomicAdd(&dlc[b], 1)] = pk[i];
    }
    for (int i = t; i < n; i += 256) {
        int b = sb[i];
        esl[sbase[b] + atomicAdd(&slc[b], 1)] = sl[i];
    }
}

// ---------------- out-degree -> out_norm (per-bucket LDS histogram) ----------------

__global__ __launch_bounds__(512) void src_hist_kernel(const unsigned short* __restrict__ esl,
                                                       const int* __restrict__ scur,
                                                       float* __restrict__ out_norm) {
    __shared__ int cnt[NPB];
    int t = threadIdx.x, b = blockIdx.x;
    cnt[t] = 0;
    __syncthreads();
    int e0 = b * CAP, e1 = scur[b];
    for (int i = e0 + t; i < e1; i += 512) atomicAdd(&cnt[esl[i]], 1);
    __syncthreads();
    int node = b * NPB + t;
    if (node < NNODES) out_norm[node] = rsqrtf((float)max(cnt[t], 1));
}

// ---------------- per-bucket fine CSR + in_norm + per-range row offsets ----------------
// Counting sort key = (dst_local<<4) | (src>>13). Also emits rro[k][node] = absolute start
// of source-range k within the node's row (k=0..13; rro[13]=row end) — consumed by the
// phased aggregate. Transposed [k][node] layout -> coalesced per-phase reads.

__global__ __launch_bounds__(512) void bucket_csr_kernel(const unsigned* __restrict__ epk,
                                                         const int* __restrict__ dcur,
                                                         int* __restrict__ rro,
                                                         float* __restrict__ in_norm,
                                                         int* __restrict__ csr_src) {
    __shared__ int hist[NKEY];   // 32KB: per-key counts -> per-key exclusive offsets
    __shared__ int lcur[NKEY];   // 32KB: scatter cursors
    __shared__ int psum[NPB];    // block scan of per-thread chunk totals
    int t = threadIdx.x, b = blockIdx.x;
    for (int i = t; i < NKEY; i += 512) { hist[i] = 0; lcur[i] = 0; }
    __syncthreads();
    int e0 = b * CAP, e1 = dcur[b];
    for (int i = e0 + t; i < e1; i += 512) {
        unsigned p = epk[i];
        int key = (int)((p >> 17) << 4) | (int)((p & 0x1FFFF) >> 13);
        atomicAdd(&hist[key], 1);
    }
    __syncthreads();
    // local serial scan: thread t owns keys [t*16, t*16+16)  (== dst_local t)
    int base_ = t << 4;
    int tot = 0;
#pragma unroll
    for (int j = 0; j < 16; j++) {
        int h = hist[base_ + j];
        hist[base_ + j] = tot;      // chunk-exclusive
        tot += h;
    }
    psum[t] = tot;
    __syncthreads();
    for (int d = 1; d < NPB; d <<= 1) {
        int u = (t >= d) ? psum[t - d] : 0;
        __syncthreads();
        psum[t] += u;
        __syncthreads();
    }
    int excl = psum[t] - tot;       // row start offset within bucket
    int node = b * NPB + t;
    if (node < NNODES) in_norm[node] = rsqrtf((float)max(tot, 1));
#pragma unroll
    for (int j = 0; j < 16; j++) hist[base_ + j] += excl;   // bucket-global exclusive
    if (node < NNODES) {
#pragma unroll
        for (int j = 0; j < 14; j++)                        // j=13: keys 13..15 empty -> row end
            rro[j * NNODES + node] = e0 + hist[base_ + j];
    }
    __syncthreads();
    for (int i = e0 + t; i < e1; i += 512) {
        unsigned p = epk[i];
        int key = (int)((p >> 17) << 4) | (int)((p & 0x1FFFF) >> 13);
        csr_src[e0 + hist[key] + atomicAdd(&lcur[key], 1)] = (int)(p & 0x1FFFF);
    }
}

// ---------------- x * out_norm -> bf16 (linear row-major pairs) ----------------

__global__ __launch_bounds__(256) void scale_to_bf16_kernel(const float* __restrict__ x,
                                                            const float* __restrict__ out_norm,
                                                            uint2* __restrict__ hs) {
    int tid = blockIdx.x * 256 + threadIdx.x;
    if (tid >= NNODES * 32) return;
    int row = tid >> 5, q = tid & 31;
    float nrm = out_norm[row];
    float4 v = *(const float4*)(x + (size_t)row * F + q * 4);
    uint2 o;
    o.x = (unsigned)f2bf(v.x * nrm) | ((unsigned)f2bf(v.y * nrm) << 16);
    o.y = (unsigned)f2bf(v.z * nrm) | ((unsigned)f2bf(v.w * nrm) << 16);
    hs[(size_t)row * 32 + q] = o;
}

// ---------------- pack all 4 weight matrices into MFMA B-fragments ----------------
// Bp[(c*4+s)*64+lane] = W[s*32+(lane>>4)*8+j][c*16+(lane&15)]

__global__ void pack_all_kernel(const float* __restrict__ W1, const float* __restrict__ W2,
                                const float* __restrict__ Wm1, const float* __restrict__ Wm2,
                                short8* __restrict__ Wp) {
    int idx = blockIdx.x * 256 + threadIdx.x;
    if (idx >= 7168) return;
    const float* W; int ncol, base;
    if (idx < 2048)      { W = W1;  ncol = 128; base = 0; }
    else if (idx < 4096) { W = W2;  ncol = 128; base = 2048; }
    else if (idx < 6144) { W = Wm1; ncol = 128; base = 4096; }
    else                 { W = Wm2; ncol = 64;  base = 6144; }
    int li = idx - base;
    int lane = li & 63, s = (li >> 6) & 3, c = li >> 8;
    int nn = c * 16 + (lane & 15);
    int k0 = s * 32 + (lane >> 4) * 8;
    short8 v;
#pragma unroll
    for (int j = 0; j < 8; j++) v[j] = (short)f2bf(W[(size_t)(k0 + j) * ncol + nn]);
    Wp[idx] = v;
}

// ---------------- aggregation: CO-RESIDENT PHASED PULL ----------------
// 16 nodes per wave -> 6250 waves = 1563 blocks ~ 6 blocks/CU: the ENTIRE grid is resident
// simultaneously. All waves sweep src-ranges k=0..12 in lockstep (R6's sort gives per-node
// range boundaries in rro), so the instantaneous gather working set is ONE 2MB range ->
// L2-resident on every XCD. Accumulators: 16 nodes x 2 fp32 in registers (static unroll).
// Inner loop is wave-uniform (readlane bounds -> SGPR loop, scalar csr load, SGPR-base
// gather): no shuffles, no masking, ~7 instrs/edge.

__global__ __launch_bounds__(256) void aggregate_kernel(const unsigned* __restrict__ hs,
                                                        const int* __restrict__ rro,
                                                        const int* __restrict__ csr_src,
                                                        const float* __restrict__ in_norm,
                                                        unsigned* __restrict__ outv) {
    int wave = threadIdx.x >> 6;
    int lane = threadIdx.x & 63;
    int wid = blockIdx.x * 4 + wave;
    int n0 = wid * 16;
    if (n0 >= NNODES) return;
    float ax[16], ay[16];
#pragma unroll
    for (int i = 0; i < 16; i++) { ax[i] = 0.f; ay[i] = 0.f; }
    int li = lane & 15;
    for (int k = 0; k < NRANGE; k++) {
        int off0 = rro[k * NNODES + n0 + li];          // starts for node n0+li
        int off1 = rro[(k + 1) * NNODES + n0 + li];    // ends
#pragma unroll
        for (int i = 0; i < 16; i++) {
            int s = __builtin_amdgcn_readlane(off0, i);
            int e = __builtin_amdgcn_readlane(off1, i);
            for (int j = s; j < e; j++) {
                int sn = csr_src[j];                   // wave-uniform -> scalar load
                unsigned u = hs[(size_t)sn * 64 + lane];
                if (i == 0)  { ax[0]  += bflo(u); ay[0]  += bfhi(u); }
                if (i == 1)  { ax[1]  += bflo(u); ay[1]  += bfhi(u); }
                if (i == 2)  { ax[2]  += bflo(u); ay[2]  += bfhi(u); }
                if (i == 3)  { ax[3]  += bflo(u); ay[3]  += bfhi(u); }
                if (i == 4)  { ax[4]  += bflo(u); ay[4]  += bfhi(u); }
                if (i == 5)  { ax[5]  += bflo(u); ay[5]  += bfhi(u); }
                if (i == 6)  { ax[6]  += bflo(u); ay[6]  += bfhi(u); }
                if (i == 7)  { ax[7]  += bflo(u); ay[7]  += bfhi(u); }
                if (i == 8)  { ax[8]  += bflo(u); ay[8]  += bfhi(u); }
                if (i == 9)  { ax[9]  += bflo(u); ay[9]  += bfhi(u); }
                if (i == 10) { ax[10] += bflo(u); ay[10] += bfhi(u); }
                if (i == 11) { ax[11] += bflo(u); ay[11] += bfhi(u); }
                if (i == 12) { ax[12] += bflo(u); ay[12] += bfhi(u); }
                if (i == 13) { ax[13] += bflo(u); ay[13] += bfhi(u); }
                if (i == 14) { ax[14] += bflo(u); ay[14] += bfhi(u); }
                if (i == 15) { ax[15] += bflo(u); ay[15] += bfhi(u); }
            }
        }
    }
#pragma unroll
    for (int i = 0; i < 16; i++) {
        float inn = in_norm[n0 + i];
        outv[(size_t)(n0 + i) * 64 + lane] =
            (unsigned)f2bf(ax[i] * inn) | ((unsigned)f2bf(ay[i] * inn) << 16);
    }
}

// ---------------- MFMA GEMM (conv layers): relu(A@W+b), optional *out_norm ----------------

template <int SCALE>
__global__ __launch_bounds__(256) void gemm_mfma_kernel(const unsigned short* __restrict__ A,
                                                        const short8* __restrict__ Bp,
                                                        const float* __restrict__ bias,
                                                        const float* __restrict__ out_norm,
                                                        unsigned short* __restrict__ Cout, int nrows) {
    int w = threadIdx.x >> 6, lane = threadIdx.x & 63;
    int m = lane & 15, quad = lane >> 4;
    int row0 = blockIdx.x * 64 + w * 16;

    int arow = min(row0 + m, nrows - 1);
    short8 afrag[4];
#pragma unroll
    for (int s = 0; s < 4; s++)
        afrag[s] = *(const short8*)(A + (size_t)arow * F + s * 32 + quad * 8);

    int baseRow = row0 + quad * 4;
    float nrm[4];
    if (SCALE) {
#pragma unroll
        for (int r = 0; r < 4; r++) nrm[r] = out_norm[min(baseRow + r, nrows - 1)];
    }

#pragma unroll
    for (int c = 0; c < 8; c++) {
        f32x4 acc = {0.f, 0.f, 0.f, 0.f};
#pragma unroll
        for (int s = 0; s < 4; s++) {
            short8 b = Bp[(c * 4 + s) * 64 + lane];
            acc = __builtin_amdgcn_mfma_f32_16x16x32_bf16(afrag[s], b, acc, 0, 0, 0);
        }
        float bc = bias[c * 16 + m];
#pragma unroll
        for (int r = 0; r < 4; r++) {
            int row = baseRow + r;
            if (row < nrows) {
                float v = fmaxf(acc[r] + bc, 0.f);
                if (SCALE) v *= nrm[r];
                Cout[(size_t)row * F + c * 16 + m] = f2bf(v);
            }
        }
    }
}

// ---------------- fused MLP head: sigmoid(relu(A@Wm1+bm1)@Wm2+bm2) ----------------

__global__ __launch_bounds__(256) void mlp_fused_kernel(const unsigned short* __restrict__ A,
                                                        const short8* __restrict__ Bp1,
                                                        const float* __restrict__ bm1,
                                                        const short8* __restrict__ Bp2,
                                                        const float* __restrict__ bm2,
                                                        float* __restrict__ out, int nrows) {
    __shared__ unsigned short h3[4][16][136];   // +8 pad: break bank conflicts
    int w = threadIdx.x >> 6, lane = threadIdx.x & 63;
    int m = lane & 15, quad = lane >> 4;
    int row0 = blockIdx.x * 64 + w * 16;

    int arow = min(row0 + m, nrows - 1);
    short8 afrag[4];
#pragma unroll
    for (int s = 0; s < 4; s++)
        afrag[s] = *(const short8*)(A + (size_t)arow * F + s * 32 + quad * 8);

#pragma unroll
    for (int c = 0; c < 8; c++) {
        f32x4 acc = {0.f, 0.f, 0.f, 0.f};
#pragma unroll
        for (int s = 0; s < 4; s++) {
            short8 b = Bp1[(c * 4 + s) * 64 + lane];
            acc = __builtin_amdgcn_mfma_f32_16x16x32_bf16(afrag[s], b, acc, 0, 0, 0);
        }
        float bc = bm1[c * 16 + m];
#pragma unroll
        for (int r = 0; r < 4; r++)
            h3[w][quad * 4 + r][c * 16 + m] = f2bf(fmaxf(acc[r] + bc, 0.f));
    }
    __syncthreads();

    short8 a2[4];
#pragma unroll
    for (int s = 0; s < 4; s++)
        a2[s] = *(const short8*)(&h3[w][m][s * 32 + quad * 8]);

    int baseRow = row0 + quad * 4;
#pragma unroll
    for (int c2 = 0; c2 < 4; c2++) {
        f32x4 acc = {0.f, 0.f, 0.f, 0.f};
#pragma unroll
        for (int s = 0; s < 4; s++) {
            short8 b = Bp2[(c2 * 4 + s) * 64 + lane];
            acc = __builtin_amdgcn_mfma_f32_16x16x32_bf16(a2[s], b, acc, 0, 0, 0);
        }
        float bc = bm2[c2 * 16 + m];
#pragma unroll
        for (int r = 0; r < 4; r++) {
            int row = baseRow + r;
            if (row < nrows)
                out[(size_t)row * 64 + c2 * 16 + m] = 1.f / (1.f + __expf(-(acc[r] + bc)));
        }
    }
}

// ---------------- launch ----------------

extern "C" void kernel_launch(void* const* d_in, const int* in_sizes, int n_in,
                              void* d_out, int out_size, void* d_ws, size_t ws_size,
                              hipStream_t stream) {
    const float* x   = (const float*)d_in[0];
    const int* src   = (const int*)d_in[1];
    const int* dst   = (const int*)d_in[2];
    const float* W1  = (const float*)d_in[3];
    const float* b1  = (const float*)d_in[4];
    const float* W2  = (const float*)d_in[5];
    const float* b2  = (const float*)d_in[6];
    const float* Wm1 = (const float*)d_in[7];
    const float* bm1 = (const float*)d_in[8];
    const float* Wm2 = (const float*)d_in[9];
    const float* bm2 = (const float*)d_in[10];
    float* out = (float*)d_out;

    char* w = (char*)d_ws;
    int* dcur          = (int*)w;   w += (size_t)(NB + 4) * 4;
    int* scur          = (int*)w;   w += (size_t)(NB + 4) * 4;
    float* out_norm    = (float*)w; w += (size_t)NNODES * 4;
    float* in_norm     = (float*)w; w += (size_t)NNODES * 4;
    int* rro           = (int*)w;   w += (size_t)14 * NNODES * 4;
    int* csr_src       = (int*)w;   w += (size_t)NB * CAP * 4;
    unsigned* epk      = (unsigned*)w; w += (size_t)NB * CAP * 4;
    unsigned short* esl= (unsigned short*)w; w += (size_t)NB * CAP * 2;
    short8* Wp         = (short8*)w; w += (size_t)7168 * 16;
    unsigned* bufX     = (unsigned*)w; w += (size_t)NNODES * 64 * 4;
    unsigned* bufY     = (unsigned*)w; w += (size_t)NNODES * 64 * 4;

    init_cursors_kernel<<<1, 256, 0, stream>>>(dcur, scur);
    dual_bin_kernel<<<(NEDGES + T2 - 1) / T2, 256, 0, stream>>>(src, dst, dcur, scur, epk, esl);
    src_hist_kernel<<<NB, 512, 0, stream>>>(esl, scur, out_norm);
    bucket_csr_kernel<<<NB, 512, 0, stream>>>(epk, dcur, rro, in_norm, csr_src);
    scale_to_bf16_kernel<<<(NNODES * 32 + 255) / 256, 256, 0, stream>>>(x, out_norm, (uint2*)bufX);
    pack_all_kernel<<<28, 256, 0, stream>>>(W1, W2, Wm1, Wm2, Wp);

    const int aggGrid = (NNODES / 16 + 3) / 4;    // 6250 waves / 4 per block = 1563 blocks
    const int gemmGrid = (NNODES + 63) / 64;

    aggregate_kernel<<<aggGrid, 256, 0, stream>>>(bufX, rro, csr_src, in_norm, bufY);
    gemm_mfma_kernel<1><<<gemmGrid, 256, 0, stream>>>((const unsigned short*)bufY, Wp, b1, out_norm,
                                                      (unsigned short*)bufX, NNODES);
    aggregate_kernel<<<aggGrid, 256, 0, stream>>>(bufX, rro, csr_src, in_norm, bufY);
    gemm_mfma_kernel<0><<<gemmGrid, 256, 0, stream>>>((const unsigned short*)bufY, Wp + 2048, b2, out_norm,
                                                      (unsigned short*)bufX, NNODES);
    mlp_fused_kernel<<<gemmGrid, 256, 0, stream>>>((const unsigned short*)bufX, Wp + 4096, bm1,
                                                   Wp + 6144, bm2, out, NNODES);
}